// Round 14
// baseline (303.263 us; speedup 1.0000x reference)
//
#include <hip/hip_runtime.h>
#include <hip/hip_fp16.h>
#include <math.h>

#define NN 100000
#define EE 1600000
#define ET (EE + NN)          // edges + self loops = 1,700,000
#define NEG 0.2f
#define MSTR 68               // k_mlp LDS row stride (floats)
#define SMASK 0x1FFFF

// CSR-build geometry (fused path, round-8 proven)
#define NBUCK 98              // ceil(NN/1024) buckets of 1024 dst nodes
#define NBLK 416              // ceil(ET/4096) partition blocks
#define BITEMS 4096           // items per partition block (256 thr x 16)
#define BCAP 20480            // bucket capacity (mean 17408, sigma~128)

typedef float4 f4;

// ---------------- init: stats=0, gcnt=0 ----------------
__global__ void k_init(float* stats, int* gcnt) {
    int i = threadIdx.x;
    if (i < 4) stats[i] = 0.f;
    if (i < NBUCK) gcnt[i] = 0;
}

// ---------------- BN statistics ----------------
__global__ void k_bnstats(const float* __restrict__ h, float* stats) {
    int gid = blockIdx.x * blockDim.x + threadIdx.x;
    int stride = gridDim.x * blockDim.x;
    float s0 = 0.f, s1 = 0.f, q0 = 0.f, q1 = 0.f;
    for (int i = gid; i < NN; i += stride) {
        float2 v = reinterpret_cast<const float2*>(h)[i];
        s0 += v.x; q0 += v.x * v.x;
        s1 += v.y; q1 += v.y * v.y;
    }
#pragma unroll
    for (int off = 32; off >= 1; off >>= 1) {
        s0 += __shfl_xor(s0, off);
        s1 += __shfl_xor(s1, off);
        q0 += __shfl_xor(q0, off);
        q1 += __shfl_xor(q1, off);
    }
    if ((threadIdx.x & 63) == 0) {
        atomicAdd(&stats[0], s0); atomicAdd(&stats[1], s1);
        atomicAdd(&stats[2], q0); atomicAdd(&stats[3], q1);
    }
}

// ---------------- layer-1 rank-2 attention coefficients ----------------
__global__ void k_coef(const float* __restrict__ W1, const float* __restrict__ as1,
                       const float* __restrict__ ad1, float* __restrict__ coef) {
    int t = threadIdx.x;
    if (t >= 8) return;
    int sd = t >> 2, hh = (t >> 1) & 1, i = t & 1;
    const float* a = sd ? ad1 : as1;
    float s = 0.f;
    for (int c = 0; c < 32; ++c) s += W1[(hh * 32 + c) * 2 + i] * a[hh * 32 + c];
    coef[t] = s;
}

// ---------------- pack MLP weights for contiguous row streams ----------------
__global__ void k_wprep(const float* __restrict__ w1, const float* __restrict__ w2,
                        const float* __restrict__ w3, const float* __restrict__ w4,
                        const float* __restrict__ w5,
                        float* __restrict__ Wt, float* __restrict__ Wt5) {
    int idx = blockIdx.x * blockDim.x + threadIdx.x;
    if (idx < 4 * 4096) {
        int L = idx >> 12;
        int r = idx & 4095;
        int q = r >> 10;
        int t = r & 1023;
        int i = t >> 4, j = t & 15;
        const float* W = (L == 0) ? w1 : (L == 1) ? w2 : (L == 2) ? w3 : w4;
        Wt[idx] = W[(q * 16 + j) * 64 + i];
    }
    if (idx < 1024) {
        int i = idx >> 4, c = idx & 15;
        int w = c >> 2, j = c & 3;
        int o = 3 * w + j;
        int ocnt = (w == 3) ? 2 : 3;
        Wt5[idx] = (j < ocnt) ? w5[o * 64 + i] : 0.f;
    }
}

// ---------------- fused CSR partition: LDS hist + atomic run reservation + scatter ----------------
__global__ void __launch_bounds__(256) k_fpart(const int* __restrict__ ei, int* gcnt,
                                               unsigned* __restrict__ pairs) {
    __shared__ int hist[NBUCK];
    __shared__ int cur[NBUCK];
    int tid = threadIdx.x, blk = blockIdx.x;
    if (tid < NBUCK) hist[tid] = 0;
    int ss[16], dd[16];
    int base = blk * BITEMS;
    __syncthreads();
#pragma unroll
    for (int it = 0; it < 16; ++it) {
        int i = base + it * 256 + tid;
        int s = 0, d = -1;
        if (i < ET) {
            if (i < EE) { s = ei[i]; d = ei[EE + i]; }
            else { s = d = i - EE; }
            atomicAdd(&hist[d >> 10], 1);
        }
        ss[it] = s; dd[it] = d;
    }
    __syncthreads();
    if (tid < NBUCK) cur[tid] = tid * BCAP + atomicAdd(&gcnt[tid], hist[tid]);
    __syncthreads();
#pragma unroll
    for (int it = 0; it < 16; ++it) {
        int d = dd[it];
        if (d >= 0) {
            int pos = atomicAdd(&cur[d >> 10], 1);
            pairs[pos] = (unsigned)ss[it] | ((unsigned)(d & 1023) << 17);
        }
    }
}

// ---------------- 98-entry exclusive scan -> real bucket offsets ----------------
__global__ void k_scan98(const int* __restrict__ gcnt, int* __restrict__ rboff) {
    __shared__ int sm[128];
    int tid = threadIdx.x;
    int v = (tid < NBUCK) ? gcnt[tid] : 0;
    sm[tid] = v;
    __syncthreads();
    for (int off = 1; off < 128; off <<= 1) {
        int t = (tid >= off) ? sm[tid - off] : 0;
        __syncthreads();
        sm[tid] += t;
        __syncthreads();
    }
    if (tid < NBUCK) rboff[tid] = sm[tid] - v;
    if (tid == 0) rboff[NBUCK] = ET;
}

// ---------------- per-bucket local CSR (rowptr + srcl) ----------------
__global__ void __launch_bounds__(1024) k_bucket(const unsigned* __restrict__ pairs,
                                                 const int* __restrict__ gcnt,
                                                 const int* __restrict__ rboff,
                                                 int* __restrict__ rowptr,
                                                 int* __restrict__ srcl) {
    __shared__ int sh[1024];
    __shared__ int se[1024];
    int b = blockIdx.x, tid = threadIdx.x;
    int cnt = gcnt[b];
    int ibase = b * BCAP;
    int obase = rboff[b];
    sh[tid] = 0;
    __syncthreads();
    for (int k = tid; k < cnt; k += 1024) atomicAdd(&sh[pairs[ibase + k] >> 17], 1);
    __syncthreads();
    int deg = sh[tid];
    se[tid] = deg;
    __syncthreads();
    for (int off = 1; off < 1024; off <<= 1) {
        int t = (tid >= off) ? se[tid - off] : 0;
        __syncthreads();
        se[tid] += t;
        __syncthreads();
    }
    int excl = se[tid] - deg;
    int node = (b << 10) + tid;
    if (node < NN) rowptr[node] = obase + excl;
    sh[tid] = obase + excl;     // cursor
    __syncthreads();
    for (int k = tid; k < cnt; k += 1024) {
        unsigned p = pairs[ibase + k];
        int pos = atomicAdd(&sh[p >> 17], 1);
        srcl[pos] = (int)(p & SMASK);
    }
    if (b == 0 && tid == 0) rowptr[NN] = ET;
}

// ---------------- layer-1 prep: BN apply + rank-2 attention scalars ----------------
__global__ void k_prep1(const float* __restrict__ h, const float* __restrict__ stats,
                        const float* __restrict__ gamma, const float* __restrict__ beta,
                        const float* __restrict__ coef,
                        f4* __restrict__ nd1, float2* __restrict__ ed1) {
    int n = blockIdx.x * blockDim.x + threadIdx.x;
    if (n >= NN) return;
    const float inv = 1.f / (float)NN;
    float mu0 = stats[0] * inv, mu1 = stats[1] * inv;
    float v0 = stats[2] * inv - mu0 * mu0;
    float v1 = stats[3] * inv - mu1 * mu1;
    float g0 = rsqrtf(v0 + 1e-5f) * gamma[0];
    float g1 = rsqrtf(v1 + 1e-5f) * gamma[1];
    float2 hv = reinterpret_cast<const float2*>(h)[n];
    float x0 = (hv.x - mu0) * g0 + beta[0];
    float x1 = (hv.y - mu1) * g1 + beta[1];
    nd1[n] = make_float4(x0 * coef[0] + x1 * coef[1], x0 * coef[2] + x1 * coef[3], x0, x1);
    ed1[n] = make_float2(x0 * coef[4] + x1 * coef[5], x0 * coef[6] + x1 * coef[7]);
}

// ---------------- layer-1 GAT: thread per dst, 16B gather (L2-resident 1.6MB) ----------------
__global__ void __launch_bounds__(256) k_gat1(
    const f4* __restrict__ nd1, const float2* __restrict__ ed1,
    const int* __restrict__ rowptr, const int* __restrict__ srcl,
    f4* __restrict__ agg1a, float2* __restrict__ agg1s) {
    int n = blockIdx.x * blockDim.x + threadIdx.x;
    if (n >= NN) return;
    int beg = rowptr[n], end = rowptr[n + 1];
    float2 ed = ed1[n];
    float A0 = 0.f, B0 = 0.f, S0 = 0.f, A1 = 0.f, B1 = 0.f, S1 = 0.f;
    for (int k = beg; k < end; ++k) {
        int s = srcl[k];
        f4 p = nd1[s];
        float e0 = p.x + ed.x;
        float e1 = p.y + ed.y;
        e0 = (e0 > 0.f) ? e0 : NEG * e0;
        e1 = (e1 > 0.f) ? e1 : NEG * e1;
        float w0 = __expf(e0);
        float w1 = __expf(e1);
        A0 += w0 * p.z; B0 += w0 * p.w; S0 += w0;
        A1 += w1 * p.z; B1 += w1 * p.w; S1 += w1;
    }
    agg1a[n] = make_float4(A0, B0, A1, B1);
    agg1s[n] = make_float2(S0, S1);
}

// ---------------- layer-1 finalize + linear(64->64) + layer-2 attention scalars ----------------
__global__ void k_xform2f(const f4* __restrict__ agg1a, const float2* __restrict__ agg1s,
                          const float* __restrict__ W1, const float* __restrict__ b1,
                          const float* __restrict__ W, const float* __restrict__ a_s,
                          const float* __restrict__ a_d,
                          __half* __restrict__ xph, float2* __restrict__ es2v,
                          float2* __restrict__ ed2v) {
    int n = blockIdx.x * blockDim.x + threadIdx.x;
    if (n >= NN) return;
    f4 ag = agg1a[n];
    float2 sg = agg1s[n];
    float r0 = 1.f / (sg.x + 1e-16f);
    float r1 = 1.f / (sg.y + 1e-16f);
    float x[64];
#pragma unroll
    for (int f = 0; f < 64; ++f) {
        float A = (f < 32) ? ag.x : ag.z;
        float B = (f < 32) ? ag.y : ag.w;
        float r = (f < 32) ? r0 : r1;
        x[f] = fmaxf((A * W1[2 * f] + B * W1[2 * f + 1]) * r + b1[f], 0.f);
    }
    float es0 = 0.f, es1 = 0.f, ed0 = 0.f, ed1 = 0.f;
    __half2* xo = reinterpret_cast<__half2*>(xph + (size_t)n * 64);
#pragma unroll 1
    for (int fq = 0; fq < 16; ++fq) {
        float vq[4];
#pragma unroll
        for (int j = 0; j < 4; ++j) {
            int f = 4 * fq + j;
            float acc = 0.f;
#pragma unroll
            for (int i = 0; i < 64; ++i) acc += W[f * 64 + i] * x[i];
            vq[j] = acc;
            float ts = acc * a_s[f], td = acc * a_d[f];
            if (fq < 8) { es0 += ts; ed0 += td; } else { es1 += ts; ed1 += td; }
        }
        xo[2 * fq]     = __floats2half2_rn(vq[0], vq[1]);
        xo[2 * fq + 1] = __floats2half2_rn(vq[2], vq[3]);
    }
    es2v[n] = make_float2(es0, es1);
    ed2v[n] = make_float2(ed0, ed1);
}

// ---------------- layer-2 GAT: wave per dst, PAIRED edges, 16 edges in flight ----------------
__global__ void __launch_bounds__(256) k_gat2(
    const __half* __restrict__ xph, const float2* __restrict__ es2v,
    const float2* __restrict__ ed2v,
    const int* __restrict__ rowptr, const int* __restrict__ srcl,
    const float* __restrict__ bias, float* __restrict__ y) {
    int wid = (blockIdx.x * blockDim.x + threadIdx.x) >> 6;
    int lane = threadIdx.x & 63;
    if (wid >= NN) return;
    int l5 = lane & 31;            // channel pair index: channels 2*l5, 2*l5+1
    int hs = lane >> 5;            // 0: even slots, 1: odd slots
    bool headhi = l5 >= 16;        // channels >=32 -> head 1
    int ch = 2 * l5;
    float2 edp = ed2v[wid];
    float edv = headhi ? edp.y : edp.x;
    int beg = rowptr[wid], end = rowptr[wid + 1];
    float sum = 0.f, a0 = 0.f, a1 = 0.f;
    int k = beg;

#define GPAIR(kk)                                                                 \
    {                                                                             \
        int s_ = srcl[(kk) + hs];                                                 \
        float2 ep_ = es2v[s_];                                                    \
        unsigned xr_ = *reinterpret_cast<const unsigned*>(&xph[(size_t)s_ * 64 + ch]); \
        float e_ = (headhi ? ep_.y : ep_.x) + edv;                                \
        e_ = (e_ > 0.f) ? e_ : NEG * e_;                                          \
        float w_ = __expf(e_);                                                    \
        float2 xv_ = __half22float2(*reinterpret_cast<const __half2*>(&xr_));     \
        sum += w_; a0 += w_ * xv_.x; a1 += w_ * xv_.y;                            \
    }

    for (; k + 16 <= end; k += 16) {
        GPAIR(k) GPAIR(k + 2) GPAIR(k + 4) GPAIR(k + 6)
        GPAIR(k + 8) GPAIR(k + 10) GPAIR(k + 12) GPAIR(k + 14)
    }
    for (; k + 8 <= end; k += 8) {
        GPAIR(k) GPAIR(k + 2) GPAIR(k + 4) GPAIR(k + 6)
    }
    for (; k < end; k += 2) {
        int idx = k + hs;
        bool valid = idx < end;
        int s_ = srcl[valid ? idx : k];
        float2 ep_ = es2v[s_];
        unsigned xr_ = *reinterpret_cast<const unsigned*>(&xph[(size_t)s_ * 64 + ch]);
        float e_ = (headhi ? ep_.y : ep_.x) + edv;
        e_ = (e_ > 0.f) ? e_ : NEG * e_;
        float w_ = valid ? __expf(e_) : 0.f;
        float2 xv_ = __half22float2(*reinterpret_cast<const __half2*>(&xr_));
        sum += w_; a0 += w_ * xv_.x; a1 += w_ * xv_.y;
    }
#undef GPAIR

    sum += __shfl_xor(sum, 32);
    a0  += __shfl_xor(a0, 32);
    a1  += __shfl_xor(a1, 32);
    if (lane < 32) {
        float rs = 1.f / (sum + 1e-16f);
        float r0 = fmaxf(a0 * rs + bias[ch], 0.f);
        float r1 = fmaxf(a1 * rs + bias[ch + 1], 0.f);
        *reinterpret_cast<float2*>(&y[(size_t)wid * 64 + ch]) = make_float2(r0, r1);
    }
}

// ---------------- fused 5-layer MLP: 256 nodes/block (4 tiles), 64 FMAs per weight row ----------------
// Wave w computes outputs [16w,16w+16) for 4 node-tiles; each weight row (s_load, uniform)
// is amortized over 4x16=64 FMAs (128cy) -> 2-deep row pipeline fully hides ~200cy latency.
__global__ void __launch_bounds__(256, 2) k_mlp(
    const float* __restrict__ hin,
    const float* __restrict__ Wt, const float* __restrict__ Wt5,
    const float* __restrict__ b1, const float* __restrict__ b2,
    const float* __restrict__ b3, const float* __restrict__ b4,
    const float* __restrict__ b5,
    float* __restrict__ out) {
    __shared__ float xs[256 * MSTR];
    int lane = threadIdx.x & 63;
    int w = __builtin_amdgcn_readfirstlane(threadIdx.x >> 6);
    int nodeBase = blockIdx.x * 256;
    int o0 = w * 16;

    // cooperative, coalesced load of 256 nodes x 64 floats into LDS
#pragma unroll
    for (int i = 0; i < 16; ++i) {
        int v = threadIdx.x + 256 * i;          // f4 id
        int nl = v >> 4;                        // local node 0..255
        int f = (v & 15) << 2;
        f4 t4 = make_float4(0.f, 0.f, 0.f, 0.f);
        if (nodeBase + nl < NN)
            t4 = reinterpret_cast<const f4*>(hin)[(size_t)(nodeBase + nl) * 16 + (v & 15)];
        *reinterpret_cast<f4*>(&xs[nl * MSTR + f]) = t4;
    }
    __syncthreads();

    float acc[4][16];
#define MLP_LAYER(L, Bp)                                                          \
    {                                                                             \
        const float* Wq = Wt + ((L) * 4 + w) * 1024;                              \
        _Pragma("unroll")                                                         \
        for (int t = 0; t < 4; ++t)                                               \
            _Pragma("unroll")                                                     \
            for (int j = 0; j < 16; ++j) acc[t][j] = Bp[o0 + j];                  \
        _Pragma("unroll")                                                         \
        for (int c = 0; c < 4; ++c) {                                             \
            float xc[4][16];                                                      \
            _Pragma("unroll")                                                     \
            for (int t = 0; t < 4; ++t)                                           \
                _Pragma("unroll")                                                 \
                for (int q = 0; q < 4; ++q) {                                     \
                    f4 tv = *reinterpret_cast<const f4*>(                         \
                        &xs[(t * 64 + lane) * MSTR + c * 16 + 4 * q]);            \
                    xc[t][4 * q] = tv.x; xc[t][4 * q + 1] = tv.y;                 \
                    xc[t][4 * q + 2] = tv.z; xc[t][4 * q + 3] = tv.w;             \
                }                                                                 \
            _Pragma("unroll")                                                     \
            for (int i = 0; i < 16; ++i) {                                        \
                const float* row = &Wq[(c * 16 + i) * 16];                        \
                float wr[16];                                                     \
                _Pragma("unroll")                                                 \
                for (int j = 0; j < 16; ++j) wr[j] = row[j];                      \
                _Pragma("unroll")                                                 \
                for (int t = 0; t < 4; ++t) {                                     \
                    float xi = xc[t][i];                                          \
                    _Pragma("unroll")                                             \
                    for (int j = 0; j < 16; ++j) acc[t][j] += wr[j] * xi;         \
                }                                                                 \
            }                                                                     \
        }                                                                         \
        __syncthreads();                                                          \
        _Pragma("unroll")                                                         \
        for (int t = 0; t < 4; ++t)                                               \
            _Pragma("unroll")                                                     \
            for (int j = 0; j < 16; j += 4)                                       \
                *reinterpret_cast<f4*>(&xs[(t * 64 + lane) * MSTR + o0 + j]) =    \
                    make_float4(fmaxf(acc[t][j], 0.f), fmaxf(acc[t][j + 1], 0.f), \
                                fmaxf(acc[t][j + 2], 0.f),                        \
                                fmaxf(acc[t][j + 3], 0.f));                       \
        __syncthreads();                                                          \
    }

    MLP_LAYER(0, b1)
    MLP_LAYER(1, b2)
    MLP_LAYER(2, b3)
    MLP_LAYER(3, b4)
#undef MLP_LAYER

    // final 64 -> 11: wave w computes outputs [3w, 3w+ocnt) for 4 tiles
    int ocnt = (w == 3) ? 2 : 3;
    int ob = w * 3;
    float a5[4][3];
#pragma unroll
    for (int t = 0; t < 4; ++t)
#pragma unroll
        for (int j = 0; j < 3; ++j) a5[t][j] = (j < ocnt) ? b5[ob + j] : 0.f;
#pragma unroll
    for (int c = 0; c < 4; ++c) {
#pragma unroll
        for (int i = 0; i < 16; ++i) {
            const float* row = &Wt5[(c * 16 + i) * 16 + 4 * w];
            float wr[3];
#pragma unroll
            for (int j = 0; j < 3; ++j) wr[j] = row[j];
#pragma unroll
            for (int t = 0; t < 4; ++t) {
                float xi = xs[(t * 64 + lane) * MSTR + c * 16 + i];
#pragma unroll
                for (int j = 0; j < 3; ++j) a5[t][j] += wr[j] * xi;
            }
        }
    }
#pragma unroll
    for (int t = 0; t < 4; ++t) {
        int node = nodeBase + t * 64 + lane;
        if (node < NN) {
            for (int j = 0; j < ocnt; ++j) out[(size_t)node * 11 + ob + j] = a5[t][j];
        }
    }
}

// ---------------- launch ----------------
extern "C" void kernel_launch(void* const* d_in, const int* in_sizes, int n_in,
                              void* d_out, int out_size, void* d_ws, size_t ws_size,
                              hipStream_t stream) {
    const float* h   = (const float*)d_in[0];
    const int*   ei  = (const int*)d_in[1];
    const float* gam = (const float*)d_in[2];
    const float* bet = (const float*)d_in[3];
    const float* W1  = (const float*)d_in[4];
    const float* as1 = (const float*)d_in[5];
    const float* ad1 = (const float*)d_in[6];
    const float* b1  = (const float*)d_in[7];
    const float* W2  = (const float*)d_in[8];
    const float* as2 = (const float*)d_in[9];
    const float* ad2 = (const float*)d_in[10];
    const float* b2  = (const float*)d_in[11];
    const float* fw1 = (const float*)d_in[12];
    const float* fb1 = (const float*)d_in[13];
    const float* fw2 = (const float*)d_in[14];
    const float* fb2 = (const float*)d_in[15];
    const float* fw3 = (const float*)d_in[16];
    const float* fb3 = (const float*)d_in[17];
    const float* fw4 = (const float*)d_in[18];
    const float* fb4 = (const float*)d_in[19];
    const float* fw5 = (const float*)d_in[20];
    const float* fb5 = (const float*)d_in[21];
    float* out = (float*)d_out;

    char* ws = (char*)d_ws;
    size_t off = 0;
    auto alloc = [&](size_t bytes) -> char* {
        char* p = ws + off;
        off += (bytes + 255) & ~(size_t)255;
        return p;
    };
    float* stats  = (float*)alloc(4 * sizeof(float));
    float* coef   = (float*)alloc(8 * sizeof(float));
    int*   gcnt   = (int*)alloc(NBUCK * sizeof(int));
    int*   rboff  = (int*)alloc((NBUCK + 1) * sizeof(int));
    int*   rowptr = (int*)alloc((size_t)(NN + 1) * sizeof(int));
    int*   srcl   = (int*)alloc((size_t)ET * sizeof(int));
    float2* es2v  = (float2*)alloc((size_t)NN * sizeof(float2));
    float2* ed2v  = (float2*)alloc((size_t)NN * sizeof(float2));
    float* Wt     = (float*)alloc((size_t)4 * 4096 * sizeof(float));
    float* Wt5    = (float*)alloc((size_t)1024 * sizeof(float));
    float* bufA   = (float*)alloc((size_t)NN * 64 * sizeof(float));   // pairs -> xph
    float* bufB   = (float*)alloc((size_t)NN * 64 * sizeof(float));
    // aliases (dead before their hosts are written):
    unsigned* pairs = (unsigned*)bufA;                    // 98*20480 u32 = 8MB; dead after k_bucket
    __half* xph   = (__half*)bufA;
    f4*     agg1a = (f4*)bufB;                            // floats [0 .. 400000)
    float2* agg1s = (float2*)(bufB + 400000);             // [400000 .. 600000)
    f4*     nd1   = (f4*)(bufB + 600000);                 // [600000 .. 1000000)
    float2* ed1   = (float2*)(bufB + 1000000);            // [1000000 .. 1200000)
    (void)ws_size; (void)in_sizes; (void)n_in; (void)out_size;

    k_init<<<1, 128, 0, stream>>>(stats, gcnt);
    k_bnstats<<<256, 256, 0, stream>>>(h, stats);
    k_coef<<<1, 64, 0, stream>>>(W1, as1, ad1, coef);
    k_wprep<<<64, 256, 0, stream>>>(fw1, fw2, fw3, fw4, fw5, Wt, Wt5);

    // fused CSR build (round-8 proven)
    k_fpart<<<NBLK, 256, 0, stream>>>(ei, gcnt, pairs);
    k_scan98<<<1, 128, 0, stream>>>(gcnt, rboff);
    k_bucket<<<NBUCK, 1024, 0, stream>>>(pairs, gcnt, rboff, rowptr, srcl);

    // GAT layer 1 (rank-2 path)
    k_prep1<<<(NN + 255) / 256, 256, 0, stream>>>(h, stats, gam, bet, coef, nd1, ed1);
    k_gat1<<<(NN + 255) / 256, 256, 0, stream>>>(nd1, ed1, rowptr, srcl, agg1a, agg1s);

    // layer-1 finalize + layer-2 transform (writes xph=bufA fp16, es2v, ed2v)
    k_xform2f<<<(NN + 255) / 256, 256, 0, stream>>>(agg1a, agg1s, W1, b1, W2, as2, ad2,
                                                    xph, es2v, ed2v);

    // GAT layer 2: paired-edge fp16 gather, 16 edges in flight per wave
    k_gat2<<<(NN * 64) / 256, 256, 0, stream>>>(xph, es2v, ed2v, rowptr, srcl, b2, bufB);

    // MLP head: 256 nodes/block, 4-tile weight-row amortization
    k_mlp<<<(NN + 255) / 256, 256, 0, stream>>>(bufB, Wt, Wt5, fb1, fb2, fb3, fb4, fb5, out);
}

// Round 15
// 245.061 us; speedup vs baseline: 1.2375x; 1.2375x over previous
//
#include <hip/hip_runtime.h>
#include <hip/hip_fp16.h>
#include <math.h>

#define NN 100000
#define EE 1600000
#define ET (EE + NN)          // edges + self loops = 1,700,000
#define NEG 0.2f
#define SMASK 0x1FFFF

// CSR-build geometry (fused path, round-8 proven)
#define NBUCK 98              // ceil(NN/1024) buckets of 1024 dst nodes
#define NBLK 416              // ceil(ET/4096) partition blocks
#define BITEMS 4096           // items per partition block (256 thr x 16)
#define BCAP 20480            // bucket capacity (mean 17408, sigma~128)

typedef float4 f4;
typedef _Float16 h8 __attribute__((ext_vector_type(8)));
typedef float f32x4 __attribute__((ext_vector_type(4)));

// ---------------- init: stats=0, gcnt=0 ----------------
__global__ void k_init(float* stats, int* gcnt) {
    int i = threadIdx.x;
    if (i < 4) stats[i] = 0.f;
    if (i < NBUCK) gcnt[i] = 0;
}

// ---------------- BN statistics ----------------
__global__ void k_bnstats(const float* __restrict__ h, float* stats) {
    int gid = blockIdx.x * blockDim.x + threadIdx.x;
    int stride = gridDim.x * blockDim.x;
    float s0 = 0.f, s1 = 0.f, q0 = 0.f, q1 = 0.f;
    for (int i = gid; i < NN; i += stride) {
        float2 v = reinterpret_cast<const float2*>(h)[i];
        s0 += v.x; q0 += v.x * v.x;
        s1 += v.y; q1 += v.y * v.y;
    }
#pragma unroll
    for (int off = 32; off >= 1; off >>= 1) {
        s0 += __shfl_xor(s0, off);
        s1 += __shfl_xor(s1, off);
        q0 += __shfl_xor(q0, off);
        q1 += __shfl_xor(q1, off);
    }
    if ((threadIdx.x & 63) == 0) {
        atomicAdd(&stats[0], s0); atomicAdd(&stats[1], s1);
        atomicAdd(&stats[2], q0); atomicAdd(&stats[3], q1);
    }
}

// ---------------- layer-1 rank-2 attention coefficients ----------------
__global__ void k_coef(const float* __restrict__ W1, const float* __restrict__ as1,
                       const float* __restrict__ ad1, float* __restrict__ coef) {
    int t = threadIdx.x;
    if (t >= 8) return;
    int sd = t >> 2, hh = (t >> 1) & 1, i = t & 1;
    const float* a = sd ? ad1 : as1;
    float s = 0.f;
    for (int c = 0; c < 32; ++c) s += W1[(hh * 32 + c) * 2 + i] * a[hh * 32 + c];
    coef[t] = s;
}

// ---------------- pack MLP weights as per-lane MFMA B-fragments (fp16 hi/lo split) ----------------
// BH/BL index = L*4096 + ks*2048 + nt*512 + lane*8 + j ;  n = nt*16+(lane&15), k = ks*32+8*(lane>>4)+j
// BH5/BL5 index = ks*512 + lane*8 + j ; n = lane&15 (pad >=11 with 0)
__global__ void k_wprep(const float* __restrict__ w1, const float* __restrict__ w2,
                        const float* __restrict__ w3, const float* __restrict__ w4,
                        const float* __restrict__ w5,
                        _Float16* __restrict__ BH, _Float16* __restrict__ BL,
                        _Float16* __restrict__ BH5, _Float16* __restrict__ BL5) {
    int idx = blockIdx.x * blockDim.x + threadIdx.x;
    if (idx < 16384) {
        int L = idx >> 12;
        int r = idx & 4095;
        int ks = r >> 11, nt = (r >> 9) & 3, lane = (r >> 3) & 63, j = r & 7;
        const float* W = (L == 0) ? w1 : (L == 1) ? w2 : (L == 2) ? w3 : w4;
        int n = nt * 16 + (lane & 15);
        int k = ks * 32 + 8 * (lane >> 4) + j;
        float v = W[n * 64 + k];
        _Float16 hi = (_Float16)v;
        BH[idx] = hi;
        BL[idx] = (_Float16)(v - (float)hi);
    }
    if (idx < 1024) {
        int ks = idx >> 9, lane = (idx >> 3) & 63, j = idx & 7;
        int n = lane & 15;
        int k = ks * 32 + 8 * (lane >> 4) + j;
        float v = (n < 11) ? w5[n * 64 + k] : 0.f;
        _Float16 hi = (_Float16)v;
        BH5[idx] = hi;
        BL5[idx] = (_Float16)(v - (float)hi);
    }
}

// ---------------- fused CSR partition: LDS hist + atomic run reservation + scatter ----------------
__global__ void __launch_bounds__(256) k_fpart(const int* __restrict__ ei, int* gcnt,
                                               unsigned* __restrict__ pairs) {
    __shared__ int hist[NBUCK];
    __shared__ int cur[NBUCK];
    int tid = threadIdx.x, blk = blockIdx.x;
    if (tid < NBUCK) hist[tid] = 0;
    int ss[16], dd[16];
    int base = blk * BITEMS;
    __syncthreads();
#pragma unroll
    for (int it = 0; it < 16; ++it) {
        int i = base + it * 256 + tid;
        int s = 0, d = -1;
        if (i < ET) {
            if (i < EE) { s = ei[i]; d = ei[EE + i]; }
            else { s = d = i - EE; }
            atomicAdd(&hist[d >> 10], 1);
        }
        ss[it] = s; dd[it] = d;
    }
    __syncthreads();
    if (tid < NBUCK) cur[tid] = tid * BCAP + atomicAdd(&gcnt[tid], hist[tid]);
    __syncthreads();
#pragma unroll
    for (int it = 0; it < 16; ++it) {
        int d = dd[it];
        if (d >= 0) {
            int pos = atomicAdd(&cur[d >> 10], 1);
            pairs[pos] = (unsigned)ss[it] | ((unsigned)(d & 1023) << 17);
        }
    }
}

// ---------------- 98-entry exclusive scan -> real bucket offsets ----------------
__global__ void k_scan98(const int* __restrict__ gcnt, int* __restrict__ rboff) {
    __shared__ int sm[128];
    int tid = threadIdx.x;
    int v = (tid < NBUCK) ? gcnt[tid] : 0;
    sm[tid] = v;
    __syncthreads();
    for (int off = 1; off < 128; off <<= 1) {
        int t = (tid >= off) ? sm[tid - off] : 0;
        __syncthreads();
        sm[tid] += t;
        __syncthreads();
    }
    if (tid < NBUCK) rboff[tid] = sm[tid] - v;
    if (tid == 0) rboff[NBUCK] = ET;
}

// ---------------- per-bucket local CSR (rowptr + srcl) ----------------
__global__ void __launch_bounds__(1024) k_bucket(const unsigned* __restrict__ pairs,
                                                 const int* __restrict__ gcnt,
                                                 const int* __restrict__ rboff,
                                                 int* __restrict__ rowptr,
                                                 int* __restrict__ srcl) {
    __shared__ int sh[1024];
    __shared__ int se[1024];
    int b = blockIdx.x, tid = threadIdx.x;
    int cnt = gcnt[b];
    int ibase = b * BCAP;
    int obase = rboff[b];
    sh[tid] = 0;
    __syncthreads();
    for (int k = tid; k < cnt; k += 1024) atomicAdd(&sh[pairs[ibase + k] >> 17], 1);
    __syncthreads();
    int deg = sh[tid];
    se[tid] = deg;
    __syncthreads();
    for (int off = 1; off < 1024; off <<= 1) {
        int t = (tid >= off) ? se[tid - off] : 0;
        __syncthreads();
        se[tid] += t;
        __syncthreads();
    }
    int excl = se[tid] - deg;
    int node = (b << 10) + tid;
    if (node < NN) rowptr[node] = obase + excl;
    sh[tid] = obase + excl;     // cursor
    __syncthreads();
    for (int k = tid; k < cnt; k += 1024) {
        unsigned p = pairs[ibase + k];
        int pos = atomicAdd(&sh[p >> 17], 1);
        srcl[pos] = (int)(p & SMASK);
    }
    if (b == 0 && tid == 0) rowptr[NN] = ET;
}

// ---------------- layer-1 prep: BN apply + rank-2 attention scalars ----------------
__global__ void k_prep1(const float* __restrict__ h, const float* __restrict__ stats,
                        const float* __restrict__ gamma, const float* __restrict__ beta,
                        const float* __restrict__ coef,
                        f4* __restrict__ nd1, float2* __restrict__ ed1) {
    int n = blockIdx.x * blockDim.x + threadIdx.x;
    if (n >= NN) return;
    const float inv = 1.f / (float)NN;
    float mu0 = stats[0] * inv, mu1 = stats[1] * inv;
    float v0 = stats[2] * inv - mu0 * mu0;
    float v1 = stats[3] * inv - mu1 * mu1;
    float g0 = rsqrtf(v0 + 1e-5f) * gamma[0];
    float g1 = rsqrtf(v1 + 1e-5f) * gamma[1];
    float2 hv = reinterpret_cast<const float2*>(h)[n];
    float x0 = (hv.x - mu0) * g0 + beta[0];
    float x1 = (hv.y - mu1) * g1 + beta[1];
    nd1[n] = make_float4(x0 * coef[0] + x1 * coef[1], x0 * coef[2] + x1 * coef[3], x0, x1);
    ed1[n] = make_float2(x0 * coef[4] + x1 * coef[5], x0 * coef[6] + x1 * coef[7]);
}

// ---------------- layer-1 GAT: thread per dst, 16B gather (L2-resident 1.6MB) ----------------
__global__ void __launch_bounds__(256) k_gat1(
    const f4* __restrict__ nd1, const float2* __restrict__ ed1,
    const int* __restrict__ rowptr, const int* __restrict__ srcl,
    f4* __restrict__ agg1a, float2* __restrict__ agg1s) {
    int n = blockIdx.x * blockDim.x + threadIdx.x;
    if (n >= NN) return;
    int beg = rowptr[n], end = rowptr[n + 1];
    float2 ed = ed1[n];
    float A0 = 0.f, B0 = 0.f, S0 = 0.f, A1 = 0.f, B1 = 0.f, S1 = 0.f;
    for (int k = beg; k < end; ++k) {
        int s = srcl[k];
        f4 p = nd1[s];
        float e0 = p.x + ed.x;
        float e1 = p.y + ed.y;
        e0 = (e0 > 0.f) ? e0 : NEG * e0;
        e1 = (e1 > 0.f) ? e1 : NEG * e1;
        float w0 = __expf(e0);
        float w1 = __expf(e1);
        A0 += w0 * p.z; B0 += w0 * p.w; S0 += w0;
        A1 += w1 * p.z; B1 += w1 * p.w; S1 += w1;
    }
    agg1a[n] = make_float4(A0, B0, A1, B1);
    agg1s[n] = make_float2(S0, S1);
}

// ---------------- layer-1 finalize + linear(64->64) + layer-2 attention scalars ----------------
__global__ void k_xform2f(const f4* __restrict__ agg1a, const float2* __restrict__ agg1s,
                          const float* __restrict__ W1, const float* __restrict__ b1,
                          const float* __restrict__ W, const float* __restrict__ a_s,
                          const float* __restrict__ a_d,
                          __half* __restrict__ xph, float2* __restrict__ es2v,
                          float2* __restrict__ ed2v) {
    int n = blockIdx.x * blockDim.x + threadIdx.x;
    if (n >= NN) return;
    f4 ag = agg1a[n];
    float2 sg = agg1s[n];
    float r0 = 1.f / (sg.x + 1e-16f);
    float r1 = 1.f / (sg.y + 1e-16f);
    float x[64];
#pragma unroll
    for (int f = 0; f < 64; ++f) {
        float A = (f < 32) ? ag.x : ag.z;
        float B = (f < 32) ? ag.y : ag.w;
        float r = (f < 32) ? r0 : r1;
        x[f] = fmaxf((A * W1[2 * f] + B * W1[2 * f + 1]) * r + b1[f], 0.f);
    }
    float es0 = 0.f, es1 = 0.f, ed0 = 0.f, ed1 = 0.f;
    __half2* xo = reinterpret_cast<__half2*>(xph + (size_t)n * 64);
#pragma unroll 1
    for (int fq = 0; fq < 16; ++fq) {
        float vq[4];
#pragma unroll
        for (int j = 0; j < 4; ++j) {
            int f = 4 * fq + j;
            float acc = 0.f;
#pragma unroll
            for (int i = 0; i < 64; ++i) acc += W[f * 64 + i] * x[i];
            vq[j] = acc;
            float ts = acc * a_s[f], td = acc * a_d[f];
            if (fq < 8) { es0 += ts; ed0 += td; } else { es1 += ts; ed1 += td; }
        }
        xo[2 * fq]     = __floats2half2_rn(vq[0], vq[1]);
        xo[2 * fq + 1] = __floats2half2_rn(vq[2], vq[3]);
    }
    es2v[n] = make_float2(es0, es1);
    ed2v[n] = make_float2(ed0, ed1);
}

// ---------------- layer-2 GAT: wave per dst, PAIRED edges, 16 edges in flight ----------------
__global__ void __launch_bounds__(256) k_gat2(
    const __half* __restrict__ xph, const float2* __restrict__ es2v,
    const float2* __restrict__ ed2v,
    const int* __restrict__ rowptr, const int* __restrict__ srcl,
    const float* __restrict__ bias, float* __restrict__ y) {
    int wid = (blockIdx.x * blockDim.x + threadIdx.x) >> 6;
    int lane = threadIdx.x & 63;
    if (wid >= NN) return;
    int l5 = lane & 31;            // channel pair index: channels 2*l5, 2*l5+1
    int hs = lane >> 5;            // 0: even slots, 1: odd slots
    bool headhi = l5 >= 16;        // channels >=32 -> head 1
    int ch = 2 * l5;
    float2 edp = ed2v[wid];
    float edv = headhi ? edp.y : edp.x;
    int beg = rowptr[wid], end = rowptr[wid + 1];
    float sum = 0.f, a0 = 0.f, a1 = 0.f;
    int k = beg;

#define GPAIR(kk)                                                                 \
    {                                                                             \
        int s_ = srcl[(kk) + hs];                                                 \
        float2 ep_ = es2v[s_];                                                    \
        unsigned xr_ = *reinterpret_cast<const unsigned*>(&xph[(size_t)s_ * 64 + ch]); \
        float e_ = (headhi ? ep_.y : ep_.x) + edv;                                \
        e_ = (e_ > 0.f) ? e_ : NEG * e_;                                          \
        float w_ = __expf(e_);                                                    \
        float2 xv_ = __half22float2(*reinterpret_cast<const __half2*>(&xr_));     \
        sum += w_; a0 += w_ * xv_.x; a1 += w_ * xv_.y;                            \
    }

    for (; k + 16 <= end; k += 16) {
        GPAIR(k) GPAIR(k + 2) GPAIR(k + 4) GPAIR(k + 6)
        GPAIR(k + 8) GPAIR(k + 10) GPAIR(k + 12) GPAIR(k + 14)
    }
    for (; k + 8 <= end; k += 8) {
        GPAIR(k) GPAIR(k + 2) GPAIR(k + 4) GPAIR(k + 6)
    }
    for (; k < end; k += 2) {
        int idx = k + hs;
        bool valid = idx < end;
        int s_ = srcl[valid ? idx : k];
        float2 ep_ = es2v[s_];
        unsigned xr_ = *reinterpret_cast<const unsigned*>(&xph[(size_t)s_ * 64 + ch]);
        float e_ = (headhi ? ep_.y : ep_.x) + edv;
        e_ = (e_ > 0.f) ? e_ : NEG * e_;
        float w_ = valid ? __expf(e_) : 0.f;
        float2 xv_ = __half22float2(*reinterpret_cast<const __half2*>(&xr_));
        sum += w_; a0 += w_ * xv_.x; a1 += w_ * xv_.y;
    }
#undef GPAIR

    sum += __shfl_xor(sum, 32);
    a0  += __shfl_xor(a0, 32);
    a1  += __shfl_xor(a1, 32);
    if (lane < 32) {
        float rs = 1.f / (sum + 1e-16f);
        float r0 = fmaxf(a0 * rs + bias[ch], 0.f);
        float r1 = fmaxf(a1 * rs + bias[ch + 1], 0.f);
        *reinterpret_cast<float2*>(&y[(size_t)wid * 64 + ch]) = make_float2(r0, r1);
    }
}

// ---------------- fused MLP via MFMA (double-fp16 split = fp32-grade accuracy) ----------------
// Block = 64 nodes; wave w owns a 16-node strip (M=16) entirely across all layers.
// Per layer: D = Ahi*Bhi + Ahi*Blo + Alo*Bhi (fp32 accum). A from wave-private LDS strip.
// A/B packed with the SAME (lane,j)->k map, so the k-permutation cancels; only
// m/n = lane&15 and C/D row=(lane>>4)*4+r col=lane&15 (HW-verified) matter.
__global__ void __launch_bounds__(256) k_mlp(
    const float* __restrict__ hin,
    const _Float16* __restrict__ BH, const _Float16* __restrict__ BL,
    const _Float16* __restrict__ BH5, const _Float16* __restrict__ BL5,
    const float* __restrict__ b1, const float* __restrict__ b2,
    const float* __restrict__ b3, const float* __restrict__ b4,
    const float* __restrict__ b5,
    float* __restrict__ out) {
    __shared__ float xs[4 * 16 * 68];      // 4 wave-strips of [16 nodes][64+pad]
    int lane = threadIdx.x & 63;
    int w = threadIdx.x >> 6;
    float* xw = &xs[w * 1088];
    int nodeBase = blockIdx.x * 64 + w * 16;
    int mrow = lane & 15;                  // A row / D col
    int kg = lane >> 4;                    // k-group

    // wave loads its 16 nodes x 64 feats (coalesced f4)
#pragma unroll
    for (int i = 0; i < 4; ++i) {
        int v = lane + 64 * i;             // f4 id 0..255
        int nl = v >> 4;
        int c4 = v & 15;
        f4 t = make_float4(0.f, 0.f, 0.f, 0.f);
        if (nodeBase + nl < NN)
            t = reinterpret_cast<const f4*>(hin)[(size_t)(nodeBase + nl) * 16 + c4];
        *reinterpret_cast<f4*>(&xw[nl * 68 + c4 * 4]) = t;
    }
    __syncthreads();

#define MAKE_A(ks)                                                                \
    f4 a0 = *reinterpret_cast<const f4*>(&xw[mrow * 68 + kg * 8 + (ks) * 32]);    \
    f4 a1 = *reinterpret_cast<const f4*>(&xw[mrow * 68 + kg * 8 + (ks) * 32 + 4]);\
    float av0 = a0.x, av1 = a0.y, av2 = a0.z, av3 = a0.w;                         \
    float av4 = a1.x, av5 = a1.y, av6 = a1.z, av7 = a1.w;                         \
    h8 ah, al;                                                                    \
    { _Float16 t;                                                                 \
      t = (_Float16)av0; ah[0] = t; al[0] = (_Float16)(av0 - (float)t);           \
      t = (_Float16)av1; ah[1] = t; al[1] = (_Float16)(av1 - (float)t);           \
      t = (_Float16)av2; ah[2] = t; al[2] = (_Float16)(av2 - (float)t);           \
      t = (_Float16)av3; ah[3] = t; al[3] = (_Float16)(av3 - (float)t);           \
      t = (_Float16)av4; ah[4] = t; al[4] = (_Float16)(av4 - (float)t);           \
      t = (_Float16)av5; ah[5] = t; al[5] = (_Float16)(av5 - (float)t);           \
      t = (_Float16)av6; ah[6] = t; al[6] = (_Float16)(av6 - (float)t);           \
      t = (_Float16)av7; ah[7] = t; al[7] = (_Float16)(av7 - (float)t); }

#define MLP_LAYER(L, Bp)                                                          \
    {                                                                             \
        const h8* bh = reinterpret_cast<const h8*>(BH + (L) * 4096);              \
        const h8* bl = reinterpret_cast<const h8*>(BL + (L) * 4096);              \
        h8 BHr[2][4], BLr[2][4];                                                  \
        _Pragma("unroll")                                                         \
        for (int ks = 0; ks < 2; ++ks)                                            \
            _Pragma("unroll")                                                     \
            for (int nt = 0; nt < 4; ++nt) {                                      \
                BHr[ks][nt] = bh[(ks * 4 + nt) * 64 + lane];                      \
                BLr[ks][nt] = bl[(ks * 4 + nt) * 64 + lane];                      \
            }                                                                     \
        float bj0 = Bp[mrow], bj1 = Bp[16 + mrow];                                \
        float bj2 = Bp[32 + mrow], bj3 = Bp[48 + mrow];                           \
        f32x4 acc0 = {0.f, 0.f, 0.f, 0.f}, acc1 = acc0, acc2 = acc0, acc3 = acc0; \
        _Pragma("unroll")                                                         \
        for (int ks = 0; ks < 2; ++ks) {                                          \
            MAKE_A(ks)                                                            \
            acc0 = __builtin_amdgcn_mfma_f32_16x16x32_f16(ah, BHr[ks][0], acc0, 0, 0, 0); \
            acc1 = __builtin_amdgcn_mfma_f32_16x16x32_f16(ah, BHr[ks][1], acc1, 0, 0, 0); \
            acc2 = __builtin_amdgcn_mfma_f32_16x16x32_f16(ah, BHr[ks][2], acc2, 0, 0, 0); \
            acc3 = __builtin_amdgcn_mfma_f32_16x16x32_f16(ah, BHr[ks][3], acc3, 0, 0, 0); \
            acc0 = __builtin_amdgcn_mfma_f32_16x16x32_f16(ah, BLr[ks][0], acc0, 0, 0, 0); \
            acc1 = __builtin_amdgcn_mfma_f32_16x16x32_f16(ah, BLr[ks][1], acc1, 0, 0, 0); \
            acc2 = __builtin_amdgcn_mfma_f32_16x16x32_f16(ah, BLr[ks][2], acc2, 0, 0, 0); \
            acc3 = __builtin_amdgcn_mfma_f32_16x16x32_f16(ah, BLr[ks][3], acc3, 0, 0, 0); \
            acc0 = __builtin_amdgcn_mfma_f32_16x16x32_f16(al, BHr[ks][0], acc0, 0, 0, 0); \
            acc1 = __builtin_amdgcn_mfma_f32_16x16x32_f16(al, BHr[ks][1], acc1, 0, 0, 0); \
            acc2 = __builtin_amdgcn_mfma_f32_16x16x32_f16(al, BHr[ks][2], acc2, 0, 0, 0); \
            acc3 = __builtin_amdgcn_mfma_f32_16x16x32_f16(al, BHr[ks][3], acc3, 0, 0, 0); \
        }                                                                         \
        __syncthreads();                                                          \
        _Pragma("unroll")                                                         \
        for (int r = 0; r < 4; ++r) {                                             \
            int row = 4 * kg + r;                                                 \
            xw[row * 68 + mrow]      = fmaxf(acc0[r] + bj0, 0.f);                 \
            xw[row * 68 + 16 + mrow] = fmaxf(acc1[r] + bj1, 0.f);                 \
            xw[row * 68 + 32 + mrow] = fmaxf(acc2[r] + bj2, 0.f);                 \
            xw[row * 68 + 48 + mrow] = fmaxf(acc3[r] + bj3, 0.f);                 \
        }                                                                         \
        __syncthreads();                                                          \
    }

    MLP_LAYER(0, b1)
    MLP_LAYER(1, b2)
    MLP_LAYER(2, b3)
    MLP_LAYER(3, b4)
#undef MLP_LAYER

    // final 64 -> 11 (single N-tile, outputs >=11 padded with zero weights)
    {
        const h8* bh = reinterpret_cast<const h8*>(BH5);
        const h8* bl = reinterpret_cast<const h8*>(BL5);
        f32x4 acc = {0.f, 0.f, 0.f, 0.f};
#pragma unroll
        for (int ks = 0; ks < 2; ++ks) {
            MAKE_A(ks)
            h8 b_h = bh[ks * 64 + lane];
            h8 b_l = bl[ks * 64 + lane];
            acc = __builtin_amdgcn_mfma_f32_16x16x32_f16(ah, b_h, acc, 0, 0, 0);
            acc = __builtin_amdgcn_mfma_f32_16x16x32_f16(ah, b_l, acc, 0, 0, 0);
            acc = __builtin_amdgcn_mfma_f32_16x16x32_f16(al, b_h, acc, 0, 0, 0);
        }
        if (mrow < 11) {
            float b5v = b5[mrow];
#pragma unroll
            for (int r = 0; r < 4; ++r) {
                int node = nodeBase + 4 * kg + r;
                if (node < NN) out[(size_t)node * 11 + mrow] = acc[r] + b5v;
            }
        }
    }
#undef MAKE_A
}

// ---------------- launch ----------------
extern "C" void kernel_launch(void* const* d_in, const int* in_sizes, int n_in,
                              void* d_out, int out_size, void* d_ws, size_t ws_size,
                              hipStream_t stream) {
    const float* h   = (const float*)d_in[0];
    const int*   ei  = (const int*)d_in[1];
    const float* gam = (const float*)d_in[2];
    const float* bet = (const float*)d_in[3];
    const float* W1  = (const float*)d_in[4];
    const float* as1 = (const float*)d_in[5];
    const float* ad1 = (const float*)d_in[6];
    const float* b1  = (const float*)d_in[7];
    const float* W2  = (const float*)d_in[8];
    const float* as2 = (const float*)d_in[9];
    const float* ad2 = (const float*)d_in[10];
    const float* b2  = (const float*)d_in[11];
    const float* fw1 = (const float*)d_in[12];
    const float* fb1 = (const float*)d_in[13];
    const float* fw2 = (const float*)d_in[14];
    const float* fb2 = (const float*)d_in[15];
    const float* fw3 = (const float*)d_in[16];
    const float* fb3 = (const float*)d_in[17];
    const float* fw4 = (const float*)d_in[18];
    const float* fb4 = (const float*)d_in[19];
    const float* fw5 = (const float*)d_in[20];
    const float* fb5 = (const float*)d_in[21];
    float* out = (float*)d_out;

    char* ws = (char*)d_ws;
    size_t off = 0;
    auto alloc = [&](size_t bytes) -> char* {
        char* p = ws + off;
        off += (bytes + 255) & ~(size_t)255;
        return p;
    };
    float* stats  = (float*)alloc(4 * sizeof(float));
    float* coef   = (float*)alloc(8 * sizeof(float));
    int*   gcnt   = (int*)alloc(NBUCK * sizeof(int));
    int*   rboff  = (int*)alloc((NBUCK + 1) * sizeof(int));
    int*   rowptr = (int*)alloc((size_t)(NN + 1) * sizeof(int));
    int*   srcl   = (int*)alloc((size_t)ET * sizeof(int));
    float2* es2v  = (float2*)alloc((size_t)NN * sizeof(float2));
    float2* ed2v  = (float2*)alloc((size_t)NN * sizeof(float2));
    _Float16* BH  = (_Float16*)alloc(16384 * sizeof(_Float16));
    _Float16* BL  = (_Float16*)alloc(16384 * sizeof(_Float16));
    _Float16* BH5 = (_Float16*)alloc(1024 * sizeof(_Float16));
    _Float16* BL5 = (_Float16*)alloc(1024 * sizeof(_Float16));
    float* bufA   = (float*)alloc((size_t)NN * 64 * sizeof(float));   // pairs -> xph
    float* bufB   = (float*)alloc((size_t)NN * 64 * sizeof(float));
    // aliases (dead before their hosts are written):
    unsigned* pairs = (unsigned*)bufA;                    // 98*20480 u32 = 8MB; dead after k_bucket
    __half* xph   = (__half*)bufA;
    f4*     agg1a = (f4*)bufB;                            // floats [0 .. 400000)
    float2* agg1s = (float2*)(bufB + 400000);             // [400000 .. 600000)
    f4*     nd1   = (f4*)(bufB + 600000);                 // [600000 .. 1000000)
    float2* ed1   = (float2*)(bufB + 1000000);            // [1000000 .. 1200000)
    (void)ws_size; (void)in_sizes; (void)n_in; (void)out_size;

    k_init<<<1, 128, 0, stream>>>(stats, gcnt);
    k_bnstats<<<256, 256, 0, stream>>>(h, stats);
    k_coef<<<1, 64, 0, stream>>>(W1, as1, ad1, coef);
    k_wprep<<<64, 256, 0, stream>>>(fw1, fw2, fw3, fw4, fw5, BH, BL, BH5, BL5);

    // fused CSR build (round-8 proven)
    k_fpart<<<NBLK, 256, 0, stream>>>(ei, gcnt, pairs);
    k_scan98<<<1, 128, 0, stream>>>(gcnt, rboff);
    k_bucket<<<NBUCK, 1024, 0, stream>>>(pairs, gcnt, rboff, rowptr, srcl);

    // GAT layer 1 (rank-2 path)
    k_prep1<<<(NN + 255) / 256, 256, 0, stream>>>(h, stats, gam, bet, coef, nd1, ed1);
    k_gat1<<<(NN + 255) / 256, 256, 0, stream>>>(nd1, ed1, rowptr, srcl, agg1a, agg1s);

    // layer-1 finalize + layer-2 transform (writes xph=bufA fp16, es2v, ed2v)
    k_xform2f<<<(NN + 255) / 256, 256, 0, stream>>>(agg1a, agg1s, W1, b1, W2, as2, ad2,
                                                    xph, es2v, ed2v);

    // GAT layer 2: paired-edge fp16 gather, 16 edges in flight per wave
    k_gat2<<<(NN * 64) / 256, 256, 0, stream>>>(xph, es2v, ed2v, rowptr, srcl, b2, bufB);

    // MLP head: MFMA with double-fp16 split
    k_mlp<<<(NN + 63) / 64, 256, 0, stream>>>(bufB, BH, BL, BH5, BL5,
                                              fb1, fb2, fb3, fb4, fb5, out);
}